// Round 1
// baseline (1519.358 us; speedup 1.0000x reference)
//
#include <hip/hip_runtime.h>
#include <math.h>

typedef unsigned short u16;
typedef unsigned int u32;
typedef __attribute__((ext_vector_type(8))) short bf8_t;   // 8 x bf16
typedef __attribute__((ext_vector_type(4))) float f4_t;

#define B_ 4
#define T_ 4096
#define C_ 1024
#define E_ 16
#define D_ 64
#define N_ 64
#define BT_ 16384
#define KC_ 65536

// ---------------- ws layout (bytes) ----------------
#define OFF_HSBF   0u            // 32MB bf16 hs  (REUSED later as ctx_scaled)
#define OFF_QT     33554432u     // 2MB  q_proj^T  (E*D, C) bf16
#define OFF_KT     35651584u
#define OFF_VT     37748736u
#define OFF_OT     39845888u     // 2MB  o_proj^T  (C, E*D) bf16
#define OFF_COMP   41943040u     // 1MB  fp32 (256,1024)
#define OFF_RW     42991616u     // 1MB  fp32 (16384,16)
#define OFF_MASK   44040192u     // 1KB  fp32 (256)
#define OFF_GIN    44041216u     // double[16]
#define OFF_FIN    44041344u     // double[16]
#define OFF_Q      44041472u     // 32MB bf16 (B,E,T,D)
#define OFF_K      77595904u
#define OFF_V      111150336u
#define WS_NEED    144704768u

__device__ __forceinline__ u16 f2bf(float f) {
  union { float f; u32 u; } v; v.f = f;
  u32 u = v.u;
  return (u16)((u + 0x7fffu + ((u >> 16) & 1u)) >> 16);
}
__device__ __forceinline__ float bf2f(u16 h) {
  union { u32 u; float f; } v; v.u = ((u32)h) << 16;
  return v.f;
}
__device__ __forceinline__ f4_t mfma16(bf8_t a, bf8_t b, f4_t c) {
  return __builtin_amdgcn_mfma_f32_16x16x32_bf16(a, b, c, 0, 0, 0);
}

// ---------------- prep: fp32 -> bf16 copy of hs ----------------
__global__ void k_cvt_hs(const float* __restrict__ src, u16* __restrict__ dst) {
  int i = (blockIdx.x * 256 + threadIdx.x) * 4;
  float4 v = *(const float4*)(src + i);
  union { u16 h[4]; uint2 u; } pk;
  pk.h[0] = f2bf(v.x); pk.h[1] = f2bf(v.y); pk.h[2] = f2bf(v.z); pk.h[3] = f2bf(v.w);
  *(uint2*)(dst + i) = pk.u;
}

// ---------------- prep: q/k/v_proj (E,C,D) -> bf16 (E*D, C) ----------------
__global__ void k_transpose_proj(const float* __restrict__ src, u16* __restrict__ dst) {
  int e = blockIdx.x, c0 = blockIdx.y * 64;
  __shared__ u16 tile[64][65];
  int t = threadIdx.x;
#pragma unroll
  for (int p = 0; p < 16; ++p) {
    int idx = p * 256 + t;
    int r = idx >> 6, d = idx & 63;               // r = local c, d contiguous
    float v = src[((size_t)e * C_ + (c0 + r)) * 64 + d];
    tile[d][r] = f2bf(v);
  }
  __syncthreads();
#pragma unroll
  for (int p = 0; p < 16; ++p) {
    int idx = p * 256 + t;
    int d = idx >> 6, r = idx & 63;
    dst[(size_t)(e * 64 + d) * C_ + c0 + r] = tile[d][r];
  }
}

// ---------------- prep: o_proj (E*D, C) -> bf16 (C, E*D) ----------------
__global__ void k_transpose_o(const float* __restrict__ src, u16* __restrict__ dst) {
  int j0 = blockIdx.x * 64, c0 = blockIdx.y * 64;
  __shared__ u16 tile[64][65];
  int t = threadIdx.x;
#pragma unroll
  for (int p = 0; p < 16; ++p) {
    int idx = p * 256 + t;
    int r = idx >> 6, cc = idx & 63;              // r = local j
    float v = src[(size_t)(j0 + r) * C_ + c0 + cc];
    tile[cc][r] = f2bf(v);
  }
  __syncthreads();
#pragma unroll
  for (int p = 0; p < 16; ++p) {
    int idx = p * 256 + t;
    int c = idx >> 6, r = idx & 63;
    dst[(size_t)(c0 + c) * C_ + j0 + r] = tile[c][r];
  }
}

// ---------------- prep: column inv-norms (double) ----------------
__global__ void k_colnorms(const float* __restrict__ sim, double* __restrict__ invn) {
  int t = threadIdx.x;
  int e = t & 15, r0 = t >> 4;
  double s = 0.0;
  for (int c = r0; c < C_; c += 16) {
    double v = (double)sim[c * E_ + e];
    s += v * v;
  }
  __shared__ double red[16][17];
  red[r0][e] = s;
  __syncthreads();
  if (t < 16) {
    double tot = 0.0;
    for (int i = 0; i < 16; ++i) tot += red[i][t];
    invn[t] = 1.0 / sqrt(tot + 1e-12);
  }
}

// ---------------- compress GEMM: (256 x 65536) @ W^T -> comp (atomics) ----------------
// tile: M=256 (all rows), N=64; grid.x = n-tiles(16), grid.y = k-splits(32)
__global__ __launch_bounds__(256) void k_compress(
    const u16* __restrict__ A, const float* __restrict__ Wt, float* __restrict__ comp) {
  const int n0 = blockIdx.x * 64;
  const int kbase = blockIdx.y * 2048;
  const int t = threadIdx.x, lane = t & 63, wv = t >> 6;
  const int r = lane & 15, qq = lane >> 4;
  __shared__ __attribute__((aligned(16))) u16 as[256 * 32];
  __shared__ __attribute__((aligned(16))) u16 bs[64 * 32];
  f4_t acc[4][4];
#pragma unroll
  for (int mi = 0; mi < 4; ++mi)
#pragma unroll
    for (int ni = 0; ni < 4; ++ni) acc[mi][ni] = (f4_t){0.f, 0.f, 0.f, 0.f};

  for (int kt = 0; kt < 64; ++kt) {
    int k0 = kbase + kt * 32;
    uint4 av[4];
#pragma unroll
    for (int p = 0; p < 4; ++p) {
      int cidx = p * 256 + t;
      int row = cidx >> 2, kc = (cidx & 3) * 8;
      av[p] = *(const uint4*)(A + (size_t)row * KC_ + k0 + kc);
    }
    float4 bv[2];
#pragma unroll
    for (int p = 0; p < 2; ++p) {
      int cidx = p * 256 + t;
      int row = cidx >> 3, kc = (cidx & 7) * 4;
      bv[p] = *(const float4*)(Wt + (size_t)(n0 + row) * KC_ + k0 + kc);
    }
    __syncthreads();
#pragma unroll
    for (int p = 0; p < 4; ++p) {
      int cidx = p * 256 + t;
      int row = cidx >> 2, kc = (cidx & 3) * 8;
      *(uint4*)&as[row * 32 + kc] = av[p];
    }
#pragma unroll
    for (int p = 0; p < 2; ++p) {
      int cidx = p * 256 + t;
      int row = cidx >> 3, kc = (cidx & 7) * 4;
      union { u16 h[4]; uint2 u; } pk;
      pk.h[0] = f2bf(bv[p].x); pk.h[1] = f2bf(bv[p].y);
      pk.h[2] = f2bf(bv[p].z); pk.h[3] = f2bf(bv[p].w);
      *(uint2*)&bs[row * 32 + kc] = pk.u;
    }
    __syncthreads();
    bf8_t af[4], bfr[4];
#pragma unroll
    for (int mi = 0; mi < 4; ++mi) af[mi] = *(const bf8_t*)&as[(wv * 64 + mi * 16 + r) * 32 + qq * 8];
#pragma unroll
    for (int ni = 0; ni < 4; ++ni) bfr[ni] = *(const bf8_t*)&bs[(ni * 16 + r) * 32 + qq * 8];
#pragma unroll
    for (int mi = 0; mi < 4; ++mi)
#pragma unroll
      for (int ni = 0; ni < 4; ++ni) acc[mi][ni] = mfma16(af[mi], bfr[ni], acc[mi][ni]);
  }
#pragma unroll
  for (int mi = 0; mi < 4; ++mi)
#pragma unroll
    for (int ni = 0; ni < 4; ++ni)
#pragma unroll
      for (int reg = 0; reg < 4; ++reg) {
        int m = wv * 64 + mi * 16 + qq * 4 + reg;
        int c = n0 + ni * 16 + r;
        atomicAdd(&comp[m * C_ + c], acc[mi][ni][reg]);
      }
}

// ---------------- g-gating -> block mask ----------------
__global__ void k_gate_g(const float* __restrict__ comp, const float* __restrict__ bias,
                         const float* __restrict__ sim, const float* __restrict__ gates,
                         const double* __restrict__ invn, const float* __restrict__ thr,
                         float* __restrict__ mask) {
  const int row = blockIdx.x;
  const int lane = threadIdx.x;
  double dot[16];
#pragma unroll
  for (int e = 0; e < 16; ++e) dot[e] = 0.0;
  double xs = 0.0;
  for (int c = lane; c < C_; c += 64) {
    float xf = fmaxf(comp[row * C_ + c] + bias[c], 0.0f);
    double x = (double)xf;
    xs += x * x;
    const float* srow = sim + c * E_;
#pragma unroll
    for (int e = 0; e < 16; ++e) dot[e] += x * (double)srow[e];
  }
#pragma unroll
  for (int off = 32; off > 0; off >>= 1) {
    xs += __shfl_xor(xs, off, 64);
#pragma unroll
    for (int e = 0; e < 16; ++e) dot[e] += __shfl_xor(dot[e], off, 64);
  }
  double xinv = 1.0 / sqrt(xs + 1e-12);
  double lg[16];
#pragma unroll
  for (int e = 0; e < 16; ++e)
    lg[e] = dot[e] * xinv * invn[e] - 1.0 / (1.0 + exp(-(double)gates[e]));
  int i1 = 0; double m1 = lg[0];
#pragma unroll
  for (int e = 1; e < 16; ++e) if (lg[e] > m1) { m1 = lg[e]; i1 = e; }
  int i2 = -1; double m2 = -1e300;
#pragma unroll
  for (int e = 0; e < 16; ++e) if (e != i1 && lg[e] > m2) { m2 = lg[e]; i2 = e; }
  int nact = 0;
#pragma unroll
  for (int e = 0; e < 16; ++e) nact += (lg[e] > 0.0) ? 1 : 0;
  float masked[16];
#pragma unroll
  for (int e = 0; e < 16; ++e) {
    bool a = nact ? (lg[e] > 0.0) : (e == i1 || e == i2);
    masked[e] = a ? (float)fmax(lg[e], 0.0) : -1e9f;
  }
  float mx = masked[0];
#pragma unroll
  for (int e = 1; e < 16; ++e) mx = fmaxf(mx, masked[e]);
  float s = 0.f, pmax = 0.f;
#pragma unroll
  for (int e = 0; e < 16; ++e) { float p = expf(masked[e] - mx); s += p; pmax = fmaxf(pmax, p); }
  float imp = pmax / s;
  if (lane == 0) mask[row] = ((imp - thr[0]) > 0.f) ? 1.f : 0.f;
}

// ---------------- f-gating -> rw (mask applied) ----------------
__global__ void k_gate_f(const float* __restrict__ hs, const float* __restrict__ sim,
                         const float* __restrict__ gates, const double* __restrict__ invn,
                         const float* __restrict__ mask, float* __restrict__ rw) {
  const int row = blockIdx.x;           // token index b*T + t
  const int lane = threadIdx.x;
  double dot[16];
#pragma unroll
  for (int e = 0; e < 16; ++e) dot[e] = 0.0;
  double xs = 0.0;
  for (int c = lane; c < C_; c += 64) {
    double x = (double)hs[(size_t)row * C_ + c];
    xs += x * x;
    const float* srow = sim + c * E_;
#pragma unroll
    for (int e = 0; e < 16; ++e) dot[e] += x * (double)srow[e];
  }
#pragma unroll
  for (int off = 32; off > 0; off >>= 1) {
    xs += __shfl_xor(xs, off, 64);
#pragma unroll
    for (int e = 0; e < 16; ++e) dot[e] += __shfl_xor(dot[e], off, 64);
  }
  double xinv = 1.0 / sqrt(xs + 1e-12);
  double lg[16];
#pragma unroll
  for (int e = 0; e < 16; ++e)
    lg[e] = dot[e] * xinv * invn[e] - 1.0 / (1.0 + exp(-(double)gates[e]));
  int i1 = 0; double m1 = lg[0];
#pragma unroll
  for (int e = 1; e < 16; ++e) if (lg[e] > m1) { m1 = lg[e]; i1 = e; }
  int i2 = -1; double m2 = -1e300;
#pragma unroll
  for (int e = 0; e < 16; ++e) if (e != i1 && lg[e] > m2) { m2 = lg[e]; i2 = e; }
  int nact = 0;
#pragma unroll
  for (int e = 0; e < 16; ++e) nact += (lg[e] > 0.0) ? 1 : 0;
  float masked[16];
#pragma unroll
  for (int e = 0; e < 16; ++e) {
    bool a = nact ? (lg[e] > 0.0) : (e == i1 || e == i2);
    masked[e] = a ? (float)fmax(lg[e], 0.0) : -1e9f;
  }
  float mx = masked[0];
#pragma unroll
  for (int e = 1; e < 16; ++e) mx = fmaxf(mx, masked[e]);
  float pr[16]; float s = 0.f;
#pragma unroll
  for (int e = 0; e < 16; ++e) { pr[e] = expf(masked[e] - mx); s += pr[e]; }
  float bm = mask[row >> 6];            // (b*64 + n)
  if (lane < 16) {
    float pv = 0.f;
#pragma unroll
    for (int e = 0; e < 16; ++e) if (lane == e) pv = pr[e];
    rw[row * 16 + lane] = (pv / s) * bm;
  }
}

// ---------------- QKV GEMM: hs_bf16 (16384,1024) @ projT -> q/k/v (B,E,T,D) bf16 ----------------
__global__ __launch_bounds__(256) void k_gemm_qkv(
    const u16* __restrict__ A,
    const u16* __restrict__ qT, const u16* __restrict__ kT, const u16* __restrict__ vT,
    u16* __restrict__ qO, u16* __restrict__ kO, u16* __restrict__ vO) {
  const u16* Bt; u16* O;
  if (blockIdx.z == 0) { Bt = qT; O = qO; }
  else if (blockIdx.z == 1) { Bt = kT; O = kO; }
  else { Bt = vT; O = vO; }
  const int m0 = blockIdx.x * 128, n0 = blockIdx.y * 128;
  const int t = threadIdx.x, lane = t & 63, wv = t >> 6;
  const int r = lane & 15, qq = lane >> 4;
  const int wm = (wv >> 1) * 64, wn = (wv & 1) * 64;
  __shared__ __attribute__((aligned(16))) u16 as[128 * 32];
  __shared__ __attribute__((aligned(16))) u16 bs[128 * 32];
  f4_t acc[4][4];
#pragma unroll
  for (int mi = 0; mi < 4; ++mi)
#pragma unroll
    for (int ni = 0; ni < 4; ++ni) acc[mi][ni] = (f4_t){0.f, 0.f, 0.f, 0.f};

  for (int kt = 0; kt < 32; ++kt) {
    int k0 = kt * 32;
    uint4 av[2], bv[2];
#pragma unroll
    for (int p = 0; p < 2; ++p) {
      int cidx = p * 256 + t;
      int row = cidx >> 2, kc = (cidx & 3) * 8;
      av[p] = *(const uint4*)(A + (size_t)(m0 + row) * C_ + k0 + kc);
      bv[p] = *(const uint4*)(Bt + (size_t)(n0 + row) * C_ + k0 + kc);
    }
    __syncthreads();
#pragma unroll
    for (int p = 0; p < 2; ++p) {
      int cidx = p * 256 + t;
      int row = cidx >> 2, kc = (cidx & 3) * 8;
      *(uint4*)&as[row * 32 + kc] = av[p];
      *(uint4*)&bs[row * 32 + kc] = bv[p];
    }
    __syncthreads();
    bf8_t af[4], bfr[4];
#pragma unroll
    for (int mi = 0; mi < 4; ++mi) af[mi] = *(const bf8_t*)&as[(wm + mi * 16 + r) * 32 + qq * 8];
#pragma unroll
    for (int ni = 0; ni < 4; ++ni) bfr[ni] = *(const bf8_t*)&bs[(wn + ni * 16 + r) * 32 + qq * 8];
#pragma unroll
    for (int mi = 0; mi < 4; ++mi)
#pragma unroll
      for (int ni = 0; ni < 4; ++ni) acc[mi][ni] = mfma16(af[mi], bfr[ni], acc[mi][ni]);
  }
#pragma unroll
  for (int mi = 0; mi < 4; ++mi)
#pragma unroll
    for (int ni = 0; ni < 4; ++ni)
#pragma unroll
      for (int reg = 0; reg < 4; ++reg) {
        int m = m0 + wm + mi * 16 + qq * 4 + reg;     // b*T + t
        int nn = n0 + wn + ni * 16 + r;               // e*64 + d
        int b = m >> 12, tt = m & 4095, e = nn >> 6, d = nn & 63;
        O[(((size_t)(b * 16 + e) * T_) + tt) * 64 + d] = f2bf(acc[mi][ni][reg]);
      }
}

// ---------------- attention per (b,e,n): RoPE + causal softmax + PV + rw scale ----------------
__global__ __launch_bounds__(256) void k_attn(
    const u16* __restrict__ Q, const u16* __restrict__ K, const u16* __restrict__ V,
    const int* __restrict__ pos, const float* __restrict__ rw, u16* __restrict__ ctxs) {
  const int blk = blockIdx.x;
  const int n = blk & 63, be = blk >> 6;
  const int b = be >> 4, e = be & 15;
  const size_t base = ((size_t)be * T_ + n * 64) * 64;
  const u16* qg = Q + base; const u16* kg = K + base; const u16* vg = V + base;
  __shared__ __attribute__((aligned(16))) u16 qs[2][64][32];   // rope'd Q, later P
  __shared__ __attribute__((aligned(16))) u16 ks[2][64][32];
  __shared__ __attribute__((aligned(16))) u16 vts[2][64][32];  // V^T: [kk][d][v&31]
  __shared__ __attribute__((aligned(16))) float sc[64][65];    // raw staging, then scores
  u16* qraw = (u16*)&sc[0][0];
  u16* kraw = qraw + 4096;
  const int t = threadIdx.x, lane = t & 63, wv = t >> 6;
  const int r = lane & 15, qq = lane >> 4;
#pragma unroll
  for (int p = 0; p < 2; ++p) {
    int c = p * 256 + t;
    int row = c >> 3, d0 = (c & 7) * 8;
    *(uint4*)(qraw + row * 64 + d0) = *(const uint4*)(qg + row * 64 + d0);
    *(uint4*)(kraw + row * 64 + d0) = *(const uint4*)(kg + row * 64 + d0);
    uint4 vv = *(const uint4*)(vg + row * 64 + d0);
    union { uint4 v; u16 h[8]; } pk; pk.v = vv;
#pragma unroll
    for (int i = 0; i < 8; ++i) {
      int d = d0 + i;
      vts[row >> 5][d][row & 31] = pk.h[i];
    }
  }
  __syncthreads();
  {
    int w = t >> 2, ds = (t & 3) * 16;
    float pf = (float)pos[b * T_ + n * 64 + w];
    u16 oq[16], ok[16];
#pragma unroll
    for (int i = 0; i < 16; ++i) {
      int d = ds + i, dm = d & 31;
      float invf = exp2f(-0.4152410118609203f * (float)dm);   // theta^(-dm/32)
      float ang = pf * invf;
      float sn, cs;
      sincosf(ang, &sn, &cs);
      float qv = bf2f(qraw[w * 64 + d]), qp2 = bf2f(qraw[w * 64 + (d ^ 32)]);
      float kv = bf2f(kraw[w * 64 + d]), kp2 = bf2f(kraw[w * 64 + (d ^ 32)]);
      float rq = (d < 32) ? -qp2 : qp2;
      float rk = (d < 32) ? -kp2 : kp2;
      oq[i] = f2bf(qv * cs + rq * sn);
      ok[i] = f2bf(kv * cs + rk * sn);
    }
#pragma unroll
    for (int i = 0; i < 16; ++i) {
      int d = ds + i;
      qs[d >> 5][w][d & 31] = oq[i];
      ks[d >> 5][w][d & 31] = ok[i];
    }
  }
  __syncthreads();
  {
    f4_t accs[4];
#pragma unroll
    for (int ni = 0; ni < 4; ++ni) accs[ni] = (f4_t){0.f, 0.f, 0.f, 0.f};
    bf8_t aq[2];
#pragma unroll
    for (int kk = 0; kk < 2; ++kk) aq[kk] = *(const bf8_t*)&qs[kk][wv * 16 + r][qq * 8];
#pragma unroll
    for (int ni = 0; ni < 4; ++ni)
#pragma unroll
      for (int kk = 0; kk < 2; ++kk) {
        bf8_t bk = *(const bf8_t*)&ks[kk][ni * 16 + r][qq * 8];
        accs[ni] = mfma16(aq[kk], bk, accs[ni]);
      }
#pragma unroll
    for (int ni = 0; ni < 4; ++ni)
#pragma unroll
      for (int reg = 0; reg < 4; ++reg)
        sc[wv * 16 + qq * 4 + reg][ni * 16 + r] = accs[ni][reg];
  }
  __syncthreads();
  if (t < 64) {
    int w = t;
    float mx = -1e30f;
    for (int j = 0; j <= w; ++j) mx = fmaxf(mx, sc[w][j] * 0.125f);
    float s = 0.f;
    for (int j = 0; j <= w; ++j) { float p = expf(sc[w][j] * 0.125f - mx); sc[w][j] = p; s += p; }
    float inv = 1.f / s;
    for (int j = 0; j < 64; ++j) {
      float p = (j <= w) ? sc[w][j] * inv : 0.f;
      qs[j >> 5][w][j & 31] = f2bf(p);
    }
  }
  __syncthreads();
  {
    f4_t accc[4];
#pragma unroll
    for (int ni = 0; ni < 4; ++ni) accc[ni] = (f4_t){0.f, 0.f, 0.f, 0.f};
    bf8_t pa[2];
#pragma unroll
    for (int kk = 0; kk < 2; ++kk) pa[kk] = *(const bf8_t*)&qs[kk][wv * 16 + r][qq * 8];
#pragma unroll
    for (int ni = 0; ni < 4; ++ni)
#pragma unroll
      for (int kk = 0; kk < 2; ++kk) {
        bf8_t bv = *(const bf8_t*)&vts[kk][ni * 16 + r][qq * 8];
        accc[ni] = mfma16(pa[kk], bv, accc[ni]);
      }
    float wt[4];
#pragma unroll
    for (int reg = 0; reg < 4; ++reg) {
      int w = wv * 16 + qq * 4 + reg;
      int tok = b * T_ + n * 64 + w;
      wt[reg] = rw[tok * 16 + e];
    }
#pragma unroll
    for (int ni = 0; ni < 4; ++ni)
#pragma unroll
      for (int reg = 0; reg < 4; ++reg) {
        int w = wv * 16 + qq * 4 + reg;
        size_t tok = (size_t)b * T_ + n * 64 + w;
        int d = ni * 16 + r;
        ctxs[tok * 1024 + e * 64 + d] = f2bf(accc[ni][reg] * wt[reg]);
      }
  }
}

// ---------------- final GEMM: ctx_scaled (16384,1024) @ oT -> out fp32 ----------------
__global__ __launch_bounds__(256) void k_gemm_out(
    const u16* __restrict__ A, const u16* __restrict__ Bt, float* __restrict__ out) {
  const int m0 = blockIdx.x * 128, n0 = blockIdx.y * 128;
  const int t = threadIdx.x, lane = t & 63, wv = t >> 6;
  const int r = lane & 15, qq = lane >> 4;
  const int wm = (wv >> 1) * 64, wn = (wv & 1) * 64;
  __shared__ __attribute__((aligned(16))) u16 as[128 * 32];
  __shared__ __attribute__((aligned(16))) u16 bs[128 * 32];
  f4_t acc[4][4];
#pragma unroll
  for (int mi = 0; mi < 4; ++mi)
#pragma unroll
    for (int ni = 0; ni < 4; ++ni) acc[mi][ni] = (f4_t){0.f, 0.f, 0.f, 0.f};

  for (int kt = 0; kt < 32; ++kt) {
    int k0 = kt * 32;
    uint4 av[2], bv[2];
#pragma unroll
    for (int p = 0; p < 2; ++p) {
      int cidx = p * 256 + t;
      int row = cidx >> 2, kc = (cidx & 3) * 8;
      av[p] = *(const uint4*)(A + (size_t)(m0 + row) * C_ + k0 + kc);
      bv[p] = *(const uint4*)(Bt + (size_t)(n0 + row) * C_ + k0 + kc);
    }
    __syncthreads();
#pragma unroll
    for (int p = 0; p < 2; ++p) {
      int cidx = p * 256 + t;
      int row = cidx >> 2, kc = (cidx & 3) * 8;
      *(uint4*)&as[row * 32 + kc] = av[p];
      *(uint4*)&bs[row * 32 + kc] = bv[p];
    }
    __syncthreads();
    bf8_t af[4], bfr[4];
#pragma unroll
    for (int mi = 0; mi < 4; ++mi) af[mi] = *(const bf8_t*)&as[(wm + mi * 16 + r) * 32 + qq * 8];
#pragma unroll
    for (int ni = 0; ni < 4; ++ni) bfr[ni] = *(const bf8_t*)&bs[(wn + ni * 16 + r) * 32 + qq * 8];
#pragma unroll
    for (int mi = 0; mi < 4; ++mi)
#pragma unroll
      for (int ni = 0; ni < 4; ++ni) acc[mi][ni] = mfma16(af[mi], bfr[ni], acc[mi][ni]);
  }
#pragma unroll
  for (int mi = 0; mi < 4; ++mi)
#pragma unroll
    for (int ni = 0; ni < 4; ++ni)
#pragma unroll
      for (int reg = 0; reg < 4; ++reg) {
        int m = m0 + wm + mi * 16 + qq * 4 + reg;
        int nn = n0 + wn + ni * 16 + r;
        out[(size_t)m * C_ + nn] = acc[mi][ni][reg];
      }
}

extern "C" void kernel_launch(void* const* d_in, const int* in_sizes, int n_in,
                              void* d_out, int out_size, void* d_ws, size_t ws_size,
                              hipStream_t stream) {
  (void)in_sizes; (void)n_in; (void)out_size;
  const float* hs     = (const float*)d_in[0];
  const int*   pos    = (const int*)d_in[1];
  const float* cw     = (const float*)d_in[2];
  const float* cb     = (const float*)d_in[3];
  const float* gsim   = (const float*)d_in[4];
  const float* ggates = (const float*)d_in[5];
  const float* thr    = (const float*)d_in[6];
  const float* fsim   = (const float*)d_in[7];
  const float* fgates = (const float*)d_in[8];
  const float* qp     = (const float*)d_in[9];
  const float* kp     = (const float*)d_in[10];
  const float* vp     = (const float*)d_in[11];
  const float* op     = (const float*)d_in[12];
  char* ws = (char*)d_ws;
  if (ws_size < (size_t)WS_NEED) return;

  u16*    hsbf  = (u16*)(ws + OFF_HSBF);
  u16*    qT    = (u16*)(ws + OFF_QT);
  u16*    kT    = (u16*)(ws + OFF_KT);
  u16*    vT    = (u16*)(ws + OFF_VT);
  u16*    oT    = (u16*)(ws + OFF_OT);
  float*  comp  = (float*)(ws + OFF_COMP);
  float*  rw    = (float*)(ws + OFF_RW);
  float*  mask  = (float*)(ws + OFF_MASK);
  double* ginv  = (double*)(ws + OFF_GIN);
  double* finv  = (double*)(ws + OFF_FIN);
  u16*    qbuf  = (u16*)(ws + OFF_Q);
  u16*    kbuf  = (u16*)(ws + OFF_K);
  u16*    vbuf  = (u16*)(ws + OFF_V);
  u16*    ctxs  = hsbf;   // reuse: hs_bf16 dead after qkv/compress GEMMs

  // prep
  k_cvt_hs<<<dim3(16384), dim3(256), 0, stream>>>(hs, hsbf);
  k_transpose_proj<<<dim3(16, 16), dim3(256), 0, stream>>>(qp, qT);
  k_transpose_proj<<<dim3(16, 16), dim3(256), 0, stream>>>(kp, kT);
  k_transpose_proj<<<dim3(16, 16), dim3(256), 0, stream>>>(vp, vT);
  k_transpose_o<<<dim3(16, 16), dim3(256), 0, stream>>>(op, oT);
  k_colnorms<<<dim3(1), dim3(256), 0, stream>>>(gsim, ginv);
  k_colnorms<<<dim3(1), dim3(256), 0, stream>>>(fsim, finv);

  // compress + gating
  hipMemsetAsync(comp, 0, 256 * C_ * sizeof(float), stream);
  k_compress<<<dim3(16, 32), dim3(256), 0, stream>>>(hsbf, cw, comp);
  k_gate_g<<<dim3(256), dim3(64), 0, stream>>>(comp, cb, gsim, ggates, ginv, thr, mask);
  k_gate_f<<<dim3(16384), dim3(64), 0, stream>>>(hs, fsim, fgates, finv, mask, rw);

  // qkv + attention + output
  k_gemm_qkv<<<dim3(128, 8, 3), dim3(256), 0, stream>>>(hsbf, qT, kT, vT, qbuf, kbuf, vbuf);
  k_attn<<<dim3(4096), dim3(256), 0, stream>>>(qbuf, kbuf, vbuf, pos, rw, ctxs);
  k_gemm_out<<<dim3(128, 8), dim3(256), 0, stream>>>(ctxs, oT, (float*)d_out);
}

// Round 2
// 1016.221 us; speedup vs baseline: 1.4951x; 1.4951x over previous
//
#include <hip/hip_runtime.h>
#include <math.h>

typedef unsigned short u16;
typedef unsigned int u32;
typedef __attribute__((ext_vector_type(8))) short bf8_t;   // 8 x bf16
typedef __attribute__((ext_vector_type(4))) float f4_t;

#define B_ 4
#define T_ 4096
#define C_ 1024
#define E_ 16
#define D_ 64
#define BT_ 16384
#define KC_ 65536

// direct global->LDS DMA, 16B per lane, dest = wave-uniform base + lane*16
#define LDS_DMA16(g, l) \
  __builtin_amdgcn_global_load_lds((const __attribute__((address_space(1))) unsigned int*)(g), \
                                   (__attribute__((address_space(3))) unsigned int*)(l), 16, 0, 0)

// ---------------- ws layout (bytes) ----------------
#define OFF_HSBF   0u            // 32MB bf16 hs  (REUSED later as ctx_scaled)
#define OFF_QT     33554432u     // 2MB  q_proj^T  (E*D, C) bf16
#define OFF_KT     35651584u
#define OFF_VT     37748736u
#define OFF_OT     39845888u     // 2MB  o_proj^T  (C, E*D) bf16
#define OFF_COMP   41943040u     // 1MB  fp32 (256,1024)
#define OFF_RW     42991616u     // 1MB  fp32 (16384,16)
#define OFF_MASK   44040192u     // 1KB  fp32 (256)
#define OFF_GIN    44041216u     // double[16]
#define OFF_FIN    44041344u     // double[16]
#define OFF_Q      44041472u     // 32MB bf16 (BT,1024); ALSO compress partials (16MB) before qkv
#define OFF_K      77595904u
#define OFF_V      111150336u
#define WS_NEED    144704768u

__device__ __forceinline__ u16 f2bf(float f) {
  union { float f; u32 u; } v; v.f = f;
  u32 u = v.u;
  return (u16)((u + 0x7fffu + ((u >> 16) & 1u)) >> 16);
}
__device__ __forceinline__ float bf2f(u16 h) {
  union { u32 u; float f; } v; v.u = ((u32)h) << 16;
  return v.f;
}
__device__ __forceinline__ f4_t mfma16(bf8_t a, bf8_t b, f4_t c) {
  return __builtin_amdgcn_mfma_f32_16x16x32_bf16(a, b, c, 0, 0, 0);
}

// ---------------- prep: fp32 -> bf16 copy of hs ----------------
__global__ void k_cvt_hs(const float* __restrict__ src, u16* __restrict__ dst) {
  int i = (blockIdx.x * 256 + threadIdx.x) * 4;
  float4 v = *(const float4*)(src + i);
  union { u16 h[4]; uint2 u; } pk;
  pk.h[0] = f2bf(v.x); pk.h[1] = f2bf(v.y); pk.h[2] = f2bf(v.z); pk.h[3] = f2bf(v.w);
  *(uint2*)(dst + i) = pk.u;
}

// ---------------- prep: q/k/v_proj (E,C,D) -> bf16 (E*D, C) ----------------
__global__ void k_transpose_proj(const float* __restrict__ src, u16* __restrict__ dst) {
  int e = blockIdx.x, c0 = blockIdx.y * 64;
  __shared__ u16 tile[64][65];
  int t = threadIdx.x;
#pragma unroll
  for (int p = 0; p < 16; ++p) {
    int idx = p * 256 + t;
    int r = idx >> 6, d = idx & 63;
    float v = src[((size_t)e * C_ + (c0 + r)) * 64 + d];
    tile[d][r] = f2bf(v);
  }
  __syncthreads();
#pragma unroll
  for (int p = 0; p < 16; ++p) {
    int idx = p * 256 + t;
    int d = idx >> 6, r = idx & 63;
    dst[(size_t)(e * 64 + d) * C_ + c0 + r] = tile[d][r];
  }
}

// ---------------- prep: o_proj (E*D, C) -> bf16 (C, E*D) ----------------
__global__ void k_transpose_o(const float* __restrict__ src, u16* __restrict__ dst) {
  int j0 = blockIdx.x * 64, c0 = blockIdx.y * 64;
  __shared__ u16 tile[64][65];
  int t = threadIdx.x;
#pragma unroll
  for (int p = 0; p < 16; ++p) {
    int idx = p * 256 + t;
    int r = idx >> 6, cc = idx & 63;
    float v = src[(size_t)(j0 + r) * C_ + c0 + cc];
    tile[cc][r] = f2bf(v);
  }
  __syncthreads();
#pragma unroll
  for (int p = 0; p < 16; ++p) {
    int idx = p * 256 + t;
    int c = idx >> 6, r = idx & 63;
    dst[(size_t)(c0 + c) * C_ + j0 + r] = tile[c][r];
  }
}

// ---------------- prep: column inv-norms (double) ----------------
__global__ void k_colnorms(const float* __restrict__ sim, double* __restrict__ invn) {
  int t = threadIdx.x;
  int e = t & 15, r0 = t >> 4;
  double s = 0.0;
  for (int c = r0; c < C_; c += 16) {
    double v = (double)sim[c * E_ + e];
    s += v * v;
  }
  __shared__ double red[16][17];
  red[r0][e] = s;
  __syncthreads();
  if (t < 16) {
    double tot = 0.0;
    for (int i = 0; i < 16; ++i) tot += red[i][t];
    invn[t] = 1.0 / sqrt(tot + 1e-12);
  }
}

// ---------------- compress GEMM: (256 x 65536) @ W^T -> split-K partials ----------------
// grid (16 n-tiles, 16 k-splits); M=256 (all rows), N=64, K per block=4096
__global__ __launch_bounds__(256) void k_compress(
    const u16* __restrict__ A, const float* __restrict__ Wt, float* __restrict__ part) {
  const int n0 = blockIdx.x * 64;
  const int kbase = blockIdx.y * 4096;
  const int t = threadIdx.x, lane = t & 63, wv = t >> 6;
  const int r = lane & 15, qq = lane >> 4;
  __shared__ __attribute__((aligned(16))) u16 as[256 * 32];
  __shared__ __attribute__((aligned(16))) u16 bs[64 * 32];
  f4_t acc[4][4];
#pragma unroll
  for (int mi = 0; mi < 4; ++mi)
#pragma unroll
    for (int ni = 0; ni < 4; ++ni) acc[mi][ni] = (f4_t){0.f, 0.f, 0.f, 0.f};

  const int la4 = lane >> 2, lk = (lane & 3) * 8;
  for (int kt = 0; kt < 128; ++kt) {
    int k0 = kbase + kt * 32;
    // A: 256x32 via DMA, 4 chunks of 16 rows per wave
#pragma unroll
    for (int c = 0; c < 4; ++c) {
      int rowA = (wv * 4 + c) * 16 + la4;
      LDS_DMA16(A + (size_t)rowA * KC_ + k0 + lk, &as[(wv * 4 + c) * 512]);
    }
    // B: 64x32 fp32 -> bf16 via VGPR
    float4 bv[2];
#pragma unroll
    for (int p = 0; p < 2; ++p) {
      int cidx = p * 256 + t;
      int row = cidx >> 3, kc = (cidx & 7) * 4;
      bv[p] = *(const float4*)(Wt + (size_t)(n0 + row) * KC_ + k0 + kc);
    }
#pragma unroll
    for (int p = 0; p < 2; ++p) {
      int cidx = p * 256 + t;
      int row = cidx >> 3, kc = (cidx & 7) * 4;
      union { u16 h[4]; uint2 u; } pk;
      pk.h[0] = f2bf(bv[p].x); pk.h[1] = f2bf(bv[p].y);
      pk.h[2] = f2bf(bv[p].z); pk.h[3] = f2bf(bv[p].w);
      *(uint2*)&bs[row * 32 + kc] = pk.u;
    }
    __syncthreads();
    bf8_t af[4], bfr[4];
#pragma unroll
    for (int mi = 0; mi < 4; ++mi) af[mi] = *(const bf8_t*)&as[(wv * 64 + mi * 16 + r) * 32 + qq * 8];
#pragma unroll
    for (int ni = 0; ni < 4; ++ni) bfr[ni] = *(const bf8_t*)&bs[(ni * 16 + r) * 32 + qq * 8];
#pragma unroll
    for (int mi = 0; mi < 4; ++mi)
#pragma unroll
      for (int ni = 0; ni < 4; ++ni) acc[mi][ni] = mfma16(af[mi], bfr[ni], acc[mi][ni]);
    __syncthreads();
  }
  float* dst = part + (size_t)blockIdx.y * (256 * C_);
#pragma unroll
  for (int mi = 0; mi < 4; ++mi)
#pragma unroll
    for (int ni = 0; ni < 4; ++ni)
#pragma unroll
      for (int reg = 0; reg < 4; ++reg) {
        int m = wv * 64 + mi * 16 + qq * 4 + reg;
        int c = n0 + ni * 16 + r;
        dst[m * C_ + c] = acc[mi][ni][reg];
      }
}

// ---------------- reduce split-K partials -> comp ----------------
__global__ void k_reduce_comp(const float* __restrict__ part, float* __restrict__ comp) {
  int i = (blockIdx.x * 256 + threadIdx.x) * 4;
  float4 s = *(const float4*)(part + i);
#pragma unroll
  for (int sp = 1; sp < 16; ++sp) {
    float4 p = *(const float4*)(part + (size_t)sp * 262144 + i);
    s.x += p.x; s.y += p.y; s.z += p.z; s.w += p.w;
  }
  *(float4*)(comp + i) = s;
}

// ---------------- g-gating -> block mask ----------------
__global__ void k_gate_g(const float* __restrict__ comp, const float* __restrict__ bias,
                         const float* __restrict__ sim, const float* __restrict__ gates,
                         const double* __restrict__ invn, const float* __restrict__ thr,
                         float* __restrict__ mask) {
  const int row = blockIdx.x;
  const int lane = threadIdx.x;
  double dot[16];
#pragma unroll
  for (int e = 0; e < 16; ++e) dot[e] = 0.0;
  double xs = 0.0;
  for (int c = lane; c < C_; c += 64) {
    float xf = fmaxf(comp[row * C_ + c] + bias[c], 0.0f);
    double x = (double)xf;
    xs += x * x;
    const float* srow = sim + c * E_;
#pragma unroll
    for (int e = 0; e < 16; ++e) dot[e] += x * (double)srow[e];
  }
#pragma unroll
  for (int off = 32; off > 0; off >>= 1) {
    xs += __shfl_xor(xs, off, 64);
#pragma unroll
    for (int e = 0; e < 16; ++e) dot[e] += __shfl_xor(dot[e], off, 64);
  }
  double xinv = 1.0 / sqrt(xs + 1e-12);
  double lg[16];
#pragma unroll
  for (int e = 0; e < 16; ++e)
    lg[e] = dot[e] * xinv * invn[e] - 1.0 / (1.0 + exp(-(double)gates[e]));
  int i1 = 0; double m1 = lg[0];
#pragma unroll
  for (int e = 1; e < 16; ++e) if (lg[e] > m1) { m1 = lg[e]; i1 = e; }
  int i2 = -1; double m2 = -1e300;
#pragma unroll
  for (int e = 0; e < 16; ++e) if (e != i1 && lg[e] > m2) { m2 = lg[e]; i2 = e; }
  int nact = 0;
#pragma unroll
  for (int e = 0; e < 16; ++e) nact += (lg[e] > 0.0) ? 1 : 0;
  float masked[16];
#pragma unroll
  for (int e = 0; e < 16; ++e) {
    bool a = nact ? (lg[e] > 0.0) : (e == i1 || e == i2);
    masked[e] = a ? (float)fmax(lg[e], 0.0) : -1e9f;
  }
  float mx = masked[0];
#pragma unroll
  for (int e = 1; e < 16; ++e) mx = fmaxf(mx, masked[e]);
  float s = 0.f, pmax = 0.f;
#pragma unroll
  for (int e = 0; e < 16; ++e) { float p = expf(masked[e] - mx); s += p; pmax = fmaxf(pmax, p); }
  float imp = pmax / s;
  if (lane == 0) mask[row] = ((imp - thr[0]) > 0.f) ? 1.f : 0.f;
}

// ---------------- f-gating -> rw (mask applied) ----------------
__global__ void k_gate_f(const float* __restrict__ hs, const float* __restrict__ sim,
                         const float* __restrict__ gates, const double* __restrict__ invn,
                         const float* __restrict__ mask, float* __restrict__ rw) {
  const int row = blockIdx.x;
  const int lane = threadIdx.x;
  double dot[16];
#pragma unroll
  for (int e = 0; e < 16; ++e) dot[e] = 0.0;
  double xs = 0.0;
  for (int c = lane; c < C_; c += 64) {
    double x = (double)hs[(size_t)row * C_ + c];
    xs += x * x;
    const float* srow = sim + c * E_;
#pragma unroll
    for (int e = 0; e < 16; ++e) dot[e] += x * (double)srow[e];
  }
#pragma unroll
  for (int off = 32; off > 0; off >>= 1) {
    xs += __shfl_xor(xs, off, 64);
#pragma unroll
    for (int e = 0; e < 16; ++e) dot[e] += __shfl_xor(dot[e], off, 64);
  }
  double xinv = 1.0 / sqrt(xs + 1e-12);
  double lg[16];
#pragma unroll
  for (int e = 0; e < 16; ++e)
    lg[e] = dot[e] * xinv * invn[e] - 1.0 / (1.0 + exp(-(double)gates[e]));
  int i1 = 0; double m1 = lg[0];
#pragma unroll
  for (int e = 1; e < 16; ++e) if (lg[e] > m1) { m1 = lg[e]; i1 = e; }
  int i2 = -1; double m2 = -1e300;
#pragma unroll
  for (int e = 0; e < 16; ++e) if (e != i1 && lg[e] > m2) { m2 = lg[e]; i2 = e; }
  int nact = 0;
#pragma unroll
  for (int e = 0; e < 16; ++e) nact += (lg[e] > 0.0) ? 1 : 0;
  float masked[16];
#pragma unroll
  for (int e = 0; e < 16; ++e) {
    bool a = nact ? (lg[e] > 0.0) : (e == i1 || e == i2);
    masked[e] = a ? (float)fmax(lg[e], 0.0) : -1e9f;
  }
  float mx = masked[0];
#pragma unroll
  for (int e = 1; e < 16; ++e) mx = fmaxf(mx, masked[e]);
  float pr[16]; float s = 0.f;
#pragma unroll
  for (int e = 0; e < 16; ++e) { pr[e] = expf(masked[e] - mx); s += pr[e]; }
  float bm = mask[row >> 6];
  if (lane < 16) {
    float pv = 0.f;
#pragma unroll
    for (int e = 0; e < 16; ++e) if (lane == e) pv = pr[e];
    rw[row * 16 + lane] = (pv / s) * bm;
  }
}

// ---------------- QKV GEMM: hs_bf16 (16384,1024) @ projT -> q/k/v [tok][e*64+d] bf16 ----------------
__global__ __launch_bounds__(256) void k_gemm_qkv(
    const u16* __restrict__ A,
    const u16* __restrict__ qT, const u16* __restrict__ kT, const u16* __restrict__ vT,
    u16* __restrict__ qO, u16* __restrict__ kO, u16* __restrict__ vO) {
  const u16* Bt; u16* O;
  if (blockIdx.z == 0) { Bt = qT; O = qO; }
  else if (blockIdx.z == 1) { Bt = kT; O = kO; }
  else { Bt = vT; O = vO; }
  const int m0 = blockIdx.x * 128, n0 = blockIdx.y * 128;
  const int t = threadIdx.x, lane = t & 63, wv = t >> 6;
  const int r = lane & 15, qq = lane >> 4;
  const int wm = (wv >> 1) * 64, wn = (wv & 1) * 64;
  __shared__ __attribute__((aligned(16))) u16 as[128 * 32];
  __shared__ __attribute__((aligned(16))) u16 bs[128 * 32];
  f4_t acc[4][4];
#pragma unroll
  for (int mi = 0; mi < 4; ++mi)
#pragma unroll
    for (int ni = 0; ni < 4; ++ni) acc[mi][ni] = (f4_t){0.f, 0.f, 0.f, 0.f};

  const int la4 = lane >> 2, lk = (lane & 3) * 8;
  for (int kt = 0; kt < 32; ++kt) {
    int k0 = kt * 32;
#pragma unroll
    for (int c = 0; c < 2; ++c) {
      int row = (wv * 2 + c) * 16 + la4;
      LDS_DMA16(A + (size_t)(m0 + row) * C_ + k0 + lk, &as[(wv * 2 + c) * 512]);
      LDS_DMA16(Bt + (size_t)(n0 + row) * C_ + k0 + lk, &bs[(wv * 2 + c) * 512]);
    }
    __syncthreads();
    bf8_t af[4], bfr[4];
#pragma unroll
    for (int mi = 0; mi < 4; ++mi) af[mi] = *(const bf8_t*)&as[(wm + mi * 16 + r) * 32 + qq * 8];
#pragma unroll
    for (int ni = 0; ni < 4; ++ni) bfr[ni] = *(const bf8_t*)&bs[(wn + ni * 16 + r) * 32 + qq * 8];
#pragma unroll
    for (int mi = 0; mi < 4; ++mi)
#pragma unroll
      for (int ni = 0; ni < 4; ++ni) acc[mi][ni] = mfma16(af[mi], bfr[ni], acc[mi][ni]);
    __syncthreads();
  }
#pragma unroll
  for (int mi = 0; mi < 4; ++mi)
#pragma unroll
    for (int ni = 0; ni < 4; ++ni)
#pragma unroll
      for (int reg = 0; reg < 4; ++reg) {
        int m = m0 + wm + mi * 16 + qq * 4 + reg;
        int nn = n0 + wn + ni * 16 + r;
        O[(size_t)m * 1024 + nn] = f2bf(acc[mi][ni][reg]);   // dense rows: no write amp
      }
}

// ---------------- attention per (b,e,n): RoPE + causal softmax + PV + rw scale ----------------
__global__ __launch_bounds__(256) void k_attn(
    const u16* __restrict__ Q, const u16* __restrict__ K, const u16* __restrict__ V,
    const int* __restrict__ pos, const float* __restrict__ rw, u16* __restrict__ ctxs) {
  const int blk = blockIdx.x;
  const int n = blk & 63, be = blk >> 6;
  const int b = be >> 4, e = be & 15;
  const size_t rbase = (size_t)(b * T_ + n * 64) * 1024 + e * 64;
  const u16* qg = Q + rbase; const u16* kg = K + rbase; const u16* vg = V + rbase;
  __shared__ __attribute__((aligned(16))) u16 qs[2][64][32];
  __shared__ __attribute__((aligned(16))) u16 ks[2][64][32];
  __shared__ __attribute__((aligned(16))) u16 vts[2][64][32];
  __shared__ __attribute__((aligned(16))) float sc[64][65];
  u16* qraw = (u16*)&sc[0][0];
  u16* kraw = qraw + 4096;
  const int t = threadIdx.x, lane = t & 63, wv = t >> 6;
  const int r = lane & 15, qq = lane >> 4;
#pragma unroll
  for (int p = 0; p < 2; ++p) {
    int c = p * 256 + t;
    int row = c >> 3, d0 = (c & 7) * 8;
    *(uint4*)(qraw + row * 64 + d0) = *(const uint4*)(qg + (size_t)row * 1024 + d0);
    *(uint4*)(kraw + row * 64 + d0) = *(const uint4*)(kg + (size_t)row * 1024 + d0);
    uint4 vv = *(const uint4*)(vg + (size_t)row * 1024 + d0);
    union { uint4 v; u16 h[8]; } pk; pk.v = vv;
#pragma unroll
    for (int i = 0; i < 8; ++i) {
      int d = d0 + i;
      vts[row >> 5][d][row & 31] = pk.h[i];
    }
  }
  __syncthreads();
  {
    int w = t >> 2, ds = (t & 3) * 16;
    float pf = (float)pos[b * T_ + n * 64 + w];
    u16 oq[16], ok[16];
#pragma unroll
    for (int i = 0; i < 16; ++i) {
      int d = ds + i, dm = d & 31;
      float invf = exp2f(-0.4152410118609203f * (float)dm);
      float ang = pf * invf;
      float sn, cs;
      sincosf(ang, &sn, &cs);
      float qv = bf2f(qraw[w * 64 + d]), qp2 = bf2f(qraw[w * 64 + (d ^ 32)]);
      float kv = bf2f(kraw[w * 64 + d]), kp2 = bf2f(kraw[w * 64 + (d ^ 32)]);
      float rq = (d < 32) ? -qp2 : qp2;
      float rk = (d < 32) ? -kp2 : kp2;
      oq[i] = f2bf(qv * cs + rq * sn);
      ok[i] = f2bf(kv * cs + rk * sn);
    }
#pragma unroll
    for (int i = 0; i < 16; ++i) {
      int d = ds + i;
      qs[d >> 5][w][d & 31] = oq[i];
      ks[d >> 5][w][d & 31] = ok[i];
    }
  }
  __syncthreads();
  {
    f4_t accs[4];
#pragma unroll
    for (int ni = 0; ni < 4; ++ni) accs[ni] = (f4_t){0.f, 0.f, 0.f, 0.f};
    bf8_t aq[2];
#pragma unroll
    for (int kk = 0; kk < 2; ++kk) aq[kk] = *(const bf8_t*)&qs[kk][wv * 16 + r][qq * 8];
#pragma unroll
    for (int ni = 0; ni < 4; ++ni)
#pragma unroll
      for (int kk = 0; kk < 2; ++kk) {
        bf8_t bk = *(const bf8_t*)&ks[kk][ni * 16 + r][qq * 8];
        accs[ni] = mfma16(aq[kk], bk, accs[ni]);
      }
#pragma unroll
    for (int ni = 0; ni < 4; ++ni)
#pragma unroll
      for (int reg = 0; reg < 4; ++reg)
        sc[wv * 16 + qq * 4 + reg][ni * 16 + r] = accs[ni][reg];
  }
  __syncthreads();
  if (t < 64) {
    int w = t;
    float mx = -1e30f;
    for (int j = 0; j <= w; ++j) mx = fmaxf(mx, sc[w][j] * 0.125f);
    float s = 0.f;
    for (int j = 0; j <= w; ++j) { float p = expf(sc[w][j] * 0.125f - mx); sc[w][j] = p; s += p; }
    float inv = 1.f / s;
    for (int j = 0; j < 64; ++j) {
      float p = (j <= w) ? sc[w][j] * inv : 0.f;
      qs[j >> 5][w][j & 31] = f2bf(p);
    }
  }
  __syncthreads();
  {
    f4_t accc[4];
#pragma unroll
    for (int ni = 0; ni < 4; ++ni) accc[ni] = (f4_t){0.f, 0.f, 0.f, 0.f};
    bf8_t pa[2];
#pragma unroll
    for (int kk = 0; kk < 2; ++kk) pa[kk] = *(const bf8_t*)&qs[kk][wv * 16 + r][qq * 8];
#pragma unroll
    for (int ni = 0; ni < 4; ++ni)
#pragma unroll
      for (int kk = 0; kk < 2; ++kk) {
        bf8_t bv = *(const bf8_t*)&vts[kk][ni * 16 + r][qq * 8];
        accc[ni] = mfma16(pa[kk], bv, accc[ni]);
      }
    float wt[4];
#pragma unroll
    for (int reg = 0; reg < 4; ++reg) {
      int w = wv * 16 + qq * 4 + reg;
      int tok = b * T_ + n * 64 + w;
      wt[reg] = rw[tok * 16 + e];
    }
#pragma unroll
    for (int ni = 0; ni < 4; ++ni)
#pragma unroll
      for (int reg = 0; reg < 4; ++reg) {
        int w = wv * 16 + qq * 4 + reg;
        size_t tok = (size_t)b * T_ + n * 64 + w;
        int d = ni * 16 + r;
        ctxs[tok * 1024 + e * 64 + d] = f2bf(accc[ni][reg] * wt[reg]);
      }
  }
}

// ---------------- final GEMM: ctx_scaled (16384,1024) @ oT -> out fp32 ----------------
__global__ __launch_bounds__(256) void k_gemm_out(
    const u16* __restrict__ A, const u16* __restrict__ Bt, float* __restrict__ out) {
  const int m0 = blockIdx.x * 128, n0 = blockIdx.y * 128;
  const int t = threadIdx.x, lane = t & 63, wv = t >> 6;
  const int r = lane & 15, qq = lane >> 4;
  const int wm = (wv >> 1) * 64, wn = (wv & 1) * 64;
  __shared__ __attribute__((aligned(16))) u16 as[128 * 32];
  __shared__ __attribute__((aligned(16))) u16 bs[128 * 32];
  f4_t acc[4][4];
#pragma unroll
  for (int mi = 0; mi < 4; ++mi)
#pragma unroll
    for (int ni = 0; ni < 4; ++ni) acc[mi][ni] = (f4_t){0.f, 0.f, 0.f, 0.f};

  const int la4 = lane >> 2, lk = (lane & 3) * 8;
  for (int kt = 0; kt < 32; ++kt) {
    int k0 = kt * 32;
#pragma unroll
    for (int c = 0; c < 2; ++c) {
      int row = (wv * 2 + c) * 16 + la4;
      LDS_DMA16(A + (size_t)(m0 + row) * C_ + k0 + lk, &as[(wv * 2 + c) * 512]);
      LDS_DMA16(Bt + (size_t)(n0 + row) * C_ + k0 + lk, &bs[(wv * 2 + c) * 512]);
    }
    __syncthreads();
    bf8_t af[4], bfr[4];
#pragma unroll
    for (int mi = 0; mi < 4; ++mi) af[mi] = *(const bf8_t*)&as[(wm + mi * 16 + r) * 32 + qq * 8];
#pragma unroll
    for (int ni = 0; ni < 4; ++ni) bfr[ni] = *(const bf8_t*)&bs[(wn + ni * 16 + r) * 32 + qq * 8];
#pragma unroll
    for (int mi = 0; mi < 4; ++mi)
#pragma unroll
      for (int ni = 0; ni < 4; ++ni) acc[mi][ni] = mfma16(af[mi], bfr[ni], acc[mi][ni]);
    __syncthreads();
  }
#pragma unroll
  for (int mi = 0; mi < 4; ++mi)
#pragma unroll
    for (int ni = 0; ni < 4; ++ni)
#pragma unroll
      for (int reg = 0; reg < 4; ++reg) {
        int m = m0 + wm + mi * 16 + qq * 4 + reg;
        int nn = n0 + wn + ni * 16 + r;
        out[(size_t)m * C_ + nn] = acc[mi][ni][reg];
      }
}

extern "C" void kernel_launch(void* const* d_in, const int* in_sizes, int n_in,
                              void* d_out, int out_size, void* d_ws, size_t ws_size,
                              hipStream_t stream) {
  (void)in_sizes; (void)n_in; (void)out_size;
  const float* hs     = (const float*)d_in[0];
  const int*   pos    = (const int*)d_in[1];
  const float* cw     = (const float*)d_in[2];
  const float* cb     = (const float*)d_in[3];
  const float* gsim   = (const float*)d_in[4];
  const float* ggates = (const float*)d_in[5];
  const float* thr    = (const float*)d_in[6];
  const float* fsim   = (const float*)d_in[7];
  const float* fgates = (const float*)d_in[8];
  const float* qp     = (const float*)d_in[9];
  const float* kp     = (const float*)d_in[10];
  const float* vp     = (const float*)d_in[11];
  const float* op     = (const float*)d_in[12];
  char* ws = (char*)d_ws;
  if (ws_size < (size_t)WS_NEED) return;

  u16*    hsbf  = (u16*)(ws + OFF_HSBF);
  u16*    qT    = (u16*)(ws + OFF_QT);
  u16*    kT    = (u16*)(ws + OFF_KT);
  u16*    vT    = (u16*)(ws + OFF_VT);
  u16*    oT    = (u16*)(ws + OFF_OT);
  float*  comp  = (float*)(ws + OFF_COMP);
  float*  rw    = (float*)(ws + OFF_RW);
  float*  mask  = (float*)(ws + OFF_MASK);
  double* ginv  = (double*)(ws + OFF_GIN);
  double* finv  = (double*)(ws + OFF_FIN);
  u16*    qbuf  = (u16*)(ws + OFF_Q);
  u16*    kbuf  = (u16*)(ws + OFF_K);
  u16*    vbuf  = (u16*)(ws + OFF_V);
  float*  partial = (float*)(ws + OFF_Q);   // 16MB, dead before qkv writes qbuf
  u16*    ctxs  = hsbf;                     // reuse: hs_bf16 dead after GEMMs

  // prep
  k_cvt_hs<<<dim3(16384), dim3(256), 0, stream>>>(hs, hsbf);
  k_transpose_proj<<<dim3(16, 16), dim3(256), 0, stream>>>(qp, qT);
  k_transpose_proj<<<dim3(16, 16), dim3(256), 0, stream>>>(kp, kT);
  k_transpose_proj<<<dim3(16, 16), dim3(256), 0, stream>>>(vp, vT);
  k_transpose_o<<<dim3(16, 16), dim3(256), 0, stream>>>(op, oT);
  k_colnorms<<<dim3(1), dim3(256), 0, stream>>>(gsim, ginv);
  k_colnorms<<<dim3(1), dim3(256), 0, stream>>>(fsim, finv);

  // compress + gating
  k_compress<<<dim3(16, 16), dim3(256), 0, stream>>>(hsbf, cw, partial);
  k_reduce_comp<<<dim3(256), dim3(256), 0, stream>>>(partial, comp);
  k_gate_g<<<dim3(256), dim3(64), 0, stream>>>(comp, cb, gsim, ggates, ginv, thr, mask);
  k_gate_f<<<dim3(16384), dim3(64), 0, stream>>>(hs, fsim, fgates, finv, mask, rw);

  // qkv + attention + output
  k_gemm_qkv<<<dim3(128, 8, 3), dim3(256), 0, stream>>>(hsbf, qT, kT, vT, qbuf, kbuf, vbuf);
  k_attn<<<dim3(4096), dim3(256), 0, stream>>>(qbuf, kbuf, vbuf, pos, rw, ctxs);
  k_gemm_out<<<dim3(128, 8), dim3(256), 0, stream>>>(ctxs, oT, (float*)d_out);
}